// Round 9
// baseline (1490.450 us; speedup 1.0000x reference)
//
#include <hip/hip_runtime.h>

#define N_NODES 100000
#define N_EDGES 1600000
#define F_INPUT 4
#define HDIM 64
#define G_GRAPHS 1000
#define C_CLS 3

#define NPB 128          // nodes per bucket (power of 2)
#define BSHIFT 7
#define NB 782           // ceil(N_NODES / NPB)
#define CBLK 196         // ceil(N_EDGES / 8192)
#define EMB_BLOCKS 6250  // N*16 / 256 (4 feats per thread)
#define HIST_BLOCKS 512

typedef __attribute__((ext_vector_type(8))) short bf16x8;
typedef __attribute__((ext_vector_type(4))) float f32x4;

__device__ __forceinline__ unsigned short f2bf(float f) {
    unsigned u = __float_as_uint(f);
    unsigned r = (u + 0x7FFF + ((u >> 16) & 1)) >> 16;  // round-to-nearest-even
    return (unsigned short)r;
}
__device__ __forceinline__ float bflo(unsigned u) {
    return __uint_as_float(u << 16);
}
__device__ __forceinline__ float bfhi(unsigned u) {
    return __uint_as_float(u & 0xFFFF0000u);
}
__device__ __forceinline__ float bf1(unsigned short s) {
    return __uint_as_float(((unsigned)s) << 16);
}

// ---------------- fused: embedding (bf16 out) + bucket histogram ----------------
__global__ __launch_bounds__(256) void k_emb_hist(
    const float* __restrict__ x, const float* __restrict__ w, const float* __restrict__ b,
    unsigned short* __restrict__ h, const int* __restrict__ dst, int* __restrict__ bcnt) {
    __shared__ int s[NB];
    if (blockIdx.x < EMB_BLOCKS) {
        int t = blockIdx.x * 256 + threadIdx.x;   // [0, N*16)
        int n = t >> 4, f0 = (t & 15) * 4;
        const float* xr = x + n * F_INPUT;
        float x0 = xr[0], x1 = xr[1], x2 = xr[2], x3 = xr[3];
        ushort4 o;
        {
            float a0 = b[f0+0] + x0*w[0*HDIM+f0+0] + x1*w[1*HDIM+f0+0] + x2*w[2*HDIM+f0+0] + x3*w[3*HDIM+f0+0];
            float a1 = b[f0+1] + x0*w[0*HDIM+f0+1] + x1*w[1*HDIM+f0+1] + x2*w[2*HDIM+f0+1] + x3*w[3*HDIM+f0+1];
            float a2 = b[f0+2] + x0*w[0*HDIM+f0+2] + x1*w[1*HDIM+f0+2] + x2*w[2*HDIM+f0+2] + x3*w[3*HDIM+f0+2];
            float a3 = b[f0+3] + x0*w[0*HDIM+f0+3] + x1*w[1*HDIM+f0+3] + x2*w[2*HDIM+f0+3] + x3*w[3*HDIM+f0+3];
            o.x = f2bf(a0); o.y = f2bf(a1); o.z = f2bf(a2); o.w = f2bf(a3);
        }
        *(ushort4*)(h + (size_t)n * HDIM + f0) = o;
    } else {
        int bb = blockIdx.x - EMB_BLOCKS;
        for (int i = threadIdx.x; i < NB; i += 256) s[i] = 0;
        __syncthreads();
        for (int e = bb * 256 + threadIdx.x; e < N_EDGES; e += HIST_BLOCKS * 256)
            atomicAdd(&s[dst[e] >> BSHIFT], 1);
        __syncthreads();
        for (int i = threadIdx.x; i < NB; i += 256)
            if (s[i]) atomicAdd(&bcnt[i], s[i]);
    }
}

// ---------------- fused: bucket-offset scan + graph boundaries ----------------
__global__ __launch_bounds__(1024) void k_boff_bounds(
    const int* __restrict__ bcnt, int* __restrict__ boff, int* __restrict__ bcur,
    const int* __restrict__ batch, int* __restrict__ goff) {
    if (blockIdx.x == 0) {
        __shared__ int s[1024];
        int t = threadIdx.x;
        int v = (t < NB) ? bcnt[t] : 0;
        s[t] = v;
        __syncthreads();
        for (int d = 1; d < 1024; d <<= 1) {
            int x2 = (t >= d) ? s[t - d] : 0;
            __syncthreads();
            s[t] += x2;
            __syncthreads();
        }
        int ex = s[t] - v;
        if (t < NB) { boff[t] = ex; bcur[t] = ex; }
        if (t == 0) boff[NB] = N_EDGES;
    } else {
        int n = (blockIdx.x - 1) * 1024 + threadIdx.x;
        if (n >= N_NODES) return;
        int bv = batch[n];
        int bp = (n == 0) ? -1 : batch[n - 1];
        for (int g = bp + 1; g <= bv; ++g) goff[g] = n;
        if (n == N_NODES - 1) {
            for (int g = bv + 1; g <= G_GRAPHS; ++g) goff[g] = N_NODES;
        }
    }
}

// ---------------- scatter edges into buckets (packed 8B records) ----------------
// record: x = src | (dloc << 17) ; y = bits of w.  8 edges/thread.
__global__ __launch_bounds__(1024) void k_bucket(const int* __restrict__ src,
                                                 const int* __restrict__ dst,
                                                 const float* __restrict__ attr,
                                                 int* __restrict__ bcur,
                                                 int2* __restrict__ bbuf) {
    __shared__ int cnt[NB];
    __shared__ int base[NB];
    for (int i = threadIdx.x; i < NB; i += 1024) cnt[i] = 0;
    __syncthreads();
    int e0 = blockIdx.x * 8192;
    int myb[8], myrank[8];
    int2 mypack[8];
#pragma unroll
    for (int k = 0; k < 8; ++k) {
        int e = e0 + k * 1024 + threadIdx.x;
        if (e < N_EDGES) {
            int d = dst[e];
            int b = d >> BSHIFT;
            myb[k] = b;
            myrank[k] = atomicAdd(&cnt[b], 1);
            mypack[k].x = src[e] | ((d & (NPB - 1)) << 17);
            mypack[k].y = __float_as_int(attr[e]);
        } else
            myb[k] = -1;
    }
    __syncthreads();
    for (int i = threadIdx.x; i < NB; i += 1024)
        base[i] = cnt[i] ? atomicAdd(&bcur[i], cnt[i]) : 0;
    __syncthreads();
#pragma unroll
    for (int k = 0; k < 8; ++k)
        if (myb[k] >= 0) bbuf[base[myb[k]] + myrank[k]] = mypack[k];
}

// ---------------- MFMA fused 3-GEMM (h bf16 in; a bf16, a2 fp32, dp bf16 out) ----------------
__global__ __launch_bounds__(256) void k_gemm3(
    const unsigned short* __restrict__ h,
    const float* __restrict__ W1, const float* __restrict__ b1,
    const float* __restrict__ W2,
    const float* __restrict__ W3, const float* __restrict__ b3,
    unsigned short* __restrict__ a_out, float* __restrict__ a2_out,
    unsigned short* __restrict__ dp_out) {
    int wave = threadIdx.x >> 6;   // coltile 0..3
    int lane = threadIdx.x & 63;
    int row = lane & 15;
    int kg = lane >> 4;            // k-group 0..3
    int base = blockIdx.x * 64;
    int col = wave * 16 + row;     // output feature

    bf16x8 Bf[3][2];
    const float* Ws[3] = {W1, W2, W3};
#pragma unroll
    for (int m = 0; m < 3; ++m)
#pragma unroll
        for (int hf = 0; hf < 2; ++hf) {
            union { bf16x8 v; unsigned short u[8]; } fr;
#pragma unroll
            for (int j = 0; j < 8; ++j) {
                int k = hf * 32 + kg * 8 + j;
                fr.u[j] = f2bf(Ws[m][k * HDIM + col]);
            }
            Bf[m][hf] = fr.v;
        }

    float bias1 = b1[col];
    float bias3 = b3[col];

    f32x4 acc[3][4];
#pragma unroll
    for (int m = 0; m < 3; ++m)
#pragma unroll
        for (int t = 0; t < 4; ++t) acc[m][t] = (f32x4){0.f, 0.f, 0.f, 0.f};

#pragma unroll
    for (int t = 0; t < 4; ++t) {
        int n = base + t * 16 + row;
        bf16x8 a0, a1;
        if (n < N_NODES) {
            const unsigned short* hr = h + (size_t)n * HDIM;
            a0 = *(const bf16x8*)(hr + kg * 8);
            a1 = *(const bf16x8*)(hr + 32 + kg * 8);
        } else {
            a0 = (bf16x8){0,0,0,0,0,0,0,0};
            a1 = (bf16x8){0,0,0,0,0,0,0,0};
        }
#pragma unroll
        for (int m = 0; m < 3; ++m) {
            acc[m][t] = __builtin_amdgcn_mfma_f32_16x16x32_bf16(a0, Bf[m][0], acc[m][t], 0, 0, 0);
            acc[m][t] = __builtin_amdgcn_mfma_f32_16x16x32_bf16(a1, Bf[m][1], acc[m][t], 0, 0, 0);
        }
    }

#pragma unroll
    for (int t = 0; t < 4; ++t) {
#pragma unroll
        for (int r = 0; r < 4; ++r) {
            int n = base + t * 16 + kg * 4 + r;
            if (n >= N_NODES) continue;
            a_out[(size_t)n * HDIM + col] = f2bf(acc[0][t][r] + bias1);
            a2_out[(size_t)n * HDIM + col] = acc[1][t][r];
            dp_out[(size_t)n * HDIM + col] = f2bf(acc[2][t][r] + bias3);
        }
    }
}

// ---------------- per-bucket LDS scatter-aggregate + epilogue ----------------
// One block per bucket (128 nodes). Unsorted records; LDS fp32 atomic accumulate.
// acc row stride 65 (+1 pad) -> random-dloc bank spread. Also accumulates wsm.
// Epilogue: h = relu(acc + dp - a2*wsm).
__global__ __launch_bounds__(512) void k_agg(const int2* __restrict__ bbuf,
                                             const int* __restrict__ boff,
                                             const unsigned short* __restrict__ a,
                                             const float* __restrict__ a2,
                                             const unsigned short* __restrict__ dp,
                                             unsigned short* __restrict__ h) {
    __shared__ float acc[NPB * 65];
    __shared__ float wsm[NPB];
    int b = blockIdx.x;
    int t = threadIdx.x;
    int lo = boff[b], hi = boff[b + 1];
    for (int i = t; i < NPB * 65; i += 512) acc[i] = 0.f;
    if (t < NPB) wsm[t] = 0.f;
    __syncthreads();

    int wave = t >> 6, lane = t & 63, slot = lane >> 3, fo = lane & 7;

#define EDGE_ADD(p, u)                                                    \
    {                                                                     \
        float w = __int_as_float(p.y);                                    \
        int dl = (p.x >> 17) & (NPB - 1);                                 \
        int ab = dl * 65 + fo * 8;                                        \
        atomicAdd(&acc[ab + 0], bflo(u.x) * w);                           \
        atomicAdd(&acc[ab + 1], bfhi(u.x) * w);                           \
        atomicAdd(&acc[ab + 2], bflo(u.y) * w);                           \
        atomicAdd(&acc[ab + 3], bfhi(u.y) * w);                           \
        atomicAdd(&acc[ab + 4], bflo(u.z) * w);                           \
        atomicAdd(&acc[ab + 5], bfhi(u.z) * w);                           \
        atomicAdd(&acc[ab + 6], bflo(u.w) * w);                           \
        atomicAdd(&acc[ab + 7], bfhi(u.w) * w);                           \
        if (fo == 0) atomicAdd(&wsm[dl], w);                              \
    }

    for (int j0 = lo + wave * 16; j0 < hi; j0 += 128) {
        int j1 = j0 + slot;
        int j2 = j0 + 8 + slot;
        bool v1 = j1 < hi, v2 = j2 < hi;
        int2 p1, p2;
        uint4 u1, u2;
        if (v1) {
            p1 = bbuf[j1];
            u1 = *(const uint4*)(a + (size_t)(p1.x & 0x1FFFF) * HDIM + fo * 8);
        }
        if (v2) {
            p2 = bbuf[j2];
            u2 = *(const uint4*)(a + (size_t)(p2.x & 0x1FFFF) * HDIM + fo * 8);
        }
        if (v1) EDGE_ADD(p1, u1)
        if (v2) EDGE_ADD(p2, u2)
    }
#undef EDGE_ADD
    __syncthreads();

    // epilogue: thread -> node t>>2, feature quarter t&3 (16 feats)
    int n_loc = t >> 2, q = t & 3;
    int n = b * NPB + n_loc;
    if (n < N_NODES) {
        float ws = wsm[n_loc];
        size_t o = (size_t)n * HDIM + q * 16;
        const float* a2r = a2 + o;
        float4 A0 = *(const float4*)(a2r + 0);
        float4 A1 = *(const float4*)(a2r + 4);
        float4 A2 = *(const float4*)(a2r + 8);
        float4 A3 = *(const float4*)(a2r + 12);
        uint4 D0 = *(const uint4*)(dp + o);
        uint4 D1 = *(const uint4*)(dp + o + 8);
        float av[16] = {A0.x, A0.y, A0.z, A0.w, A1.x, A1.y, A1.z, A1.w,
                        A2.x, A2.y, A2.z, A2.w, A3.x, A3.y, A3.z, A3.w};
        float dv[16] = {bflo(D0.x), bfhi(D0.x), bflo(D0.y), bfhi(D0.y),
                        bflo(D0.z), bfhi(D0.z), bflo(D0.w), bfhi(D0.w),
                        bflo(D1.x), bfhi(D1.x), bflo(D1.y), bfhi(D1.y),
                        bflo(D1.z), bfhi(D1.z), bflo(D1.w), bfhi(D1.w)};
        int lb = n_loc * 65 + q * 16;
        unsigned rw[8];
#pragma unroll
        for (int i = 0; i < 8; ++i) {
            float r0 = fmaxf(acc[lb + 2 * i]     + dv[2 * i]     - av[2 * i]     * ws, 0.f);
            float r1 = fmaxf(acc[lb + 2 * i + 1] + dv[2 * i + 1] - av[2 * i + 1] * ws, 0.f);
            rw[i] = (unsigned)f2bf(r0) | ((unsigned)f2bf(r1) << 16);
        }
        *(uint4*)(h + o) = make_uint4(rw[0], rw[1], rw[2], rw[3]);
        *(uint4*)(h + o + 8) = make_uint4(rw[4], rw[5], rw[6], rw[7]);
    }
}

// ---------------- fused mean pool + MLP head: one block per graph ----------------
__global__ __launch_bounds__(128) void k_poolhead(const unsigned short* __restrict__ h,
                                                  const int* __restrict__ goff,
                                                  const float* __restrict__ W1,
                                                  const float* __restrict__ b1,
                                                  const float* __restrict__ W2,
                                                  const float* __restrict__ b2,
                                                  float* __restrict__ out) {
    int g = blockIdx.x;
    __shared__ float part[128];
    __shared__ float sx[HDIM];
    __shared__ float sy[2 * HDIM];
    int t = threadIdx.x;
    int lo = goff[g], hi = goff[g + 1];
    int f = t & 63, half = t >> 6;
    float acc = 0.f;
    for (int n = lo + half; n < hi; n += 2) acc += bf1(h[(size_t)n * HDIM + f]);
    part[t] = acc;
    __syncthreads();
    if (t < HDIM) sx[t] = (part[t] + part[t + 64]) / fmaxf((float)(hi - lo), 1.f);
    __syncthreads();
    float a1 = b1[t];
    for (int k = 0; k < HDIM; ++k) a1 += sx[k] * W1[k * 2 * HDIM + t];
    sy[t] = fmaxf(a1, 0.f);
    __syncthreads();
    if (t < C_CLS) {
        float o = b2[t];
        for (int k = 0; k < 2 * HDIM; ++k) o += sy[k] * W2[k * C_CLS + t];
        out[g * C_CLS + t] = o;
    }
}

extern "C" void kernel_launch(void* const* d_in, const int* in_sizes, int n_in,
                              void* d_out, int out_size, void* d_ws, size_t ws_size,
                              hipStream_t stream) {
    const float* x      = (const float*)d_in[0];
    const int*   ei     = (const int*)d_in[1];
    const float* eattr  = (const float*)d_in[2];
    const int*   batch  = (const int*)d_in[3];
    const float* w_emb  = (const float*)d_in[4];
    const float* b_emb  = (const float*)d_in[5];
    const float* lin1_w = (const float*)d_in[6];
    const float* lin1_b = (const float*)d_in[7];
    const float* lin2_w = (const float*)d_in[8];
    const float* lin3_w = (const float*)d_in[9];
    const float* lin3_b = (const float*)d_in[10];
    const float* mlp_w1 = (const float*)d_in[11];
    const float* mlp_b1 = (const float*)d_in[12];
    const float* mlp_w2 = (const float*)d_in[13];
    const float* mlp_b2 = (const float*)d_in[14];
    float* out = (float*)d_out;

    const int* src = ei;
    const int* dst = ei + N_EDGES;

    const size_t NH = (size_t)N_NODES * HDIM;
    unsigned short* h   = (unsigned short*)d_ws;     // NH bf16
    unsigned short* abf = h + NH;                    // NH bf16
    unsigned short* dpb = abf + NH;                  // NH bf16
    float* a2f  = (float*)(dpb + NH);                // NH fp32
    int2* bbuf  = (int2*)(a2f + NH);                 // E
    int* bcnt   = (int*)(bbuf + N_EDGES);            // NB (zeroed)
    int* bcur   = bcnt + NB;                         // NB
    int* boff   = bcur + NB;                         // NB+1
    int* goff   = boff + NB + 1;                     // G+1

    hipMemsetAsync(bcnt, 0, NB * sizeof(int), stream);

    k_emb_hist<<<EMB_BLOCKS + HIST_BLOCKS, 256, 0, stream>>>(x, w_emb, b_emb, h, dst, bcnt);
    k_boff_bounds<<<1 + (N_NODES + 1023) / 1024, 1024, 0, stream>>>(bcnt, boff, bcur, batch, goff);
    k_bucket<<<CBLK, 1024, 0, stream>>>(src, dst, eattr, bcur, bbuf);

    int gemm_blocks = (N_NODES + 63) / 64;

    for (int l = 0; l < 2; ++l) {
        const float* W1 = lin1_w + l * HDIM * HDIM;
        const float* B1 = lin1_b + l * HDIM;
        const float* W2 = lin2_w + l * HDIM * HDIM;
        const float* W3 = lin3_w + l * HDIM * HDIM;
        const float* B3 = lin3_b + l * HDIM;
        k_gemm3<<<gemm_blocks, 256, 0, stream>>>(h, W1, B1, W2, W3, B3, abf, a2f, dpb);
        k_agg<<<NB, 512, 0, stream>>>(bbuf, boff, abf, a2f, dpb, h);
    }

    k_poolhead<<<G_GRAPHS, 128, 0, stream>>>(h, goff, mlp_w1, mlp_b1, mlp_w2, mlp_b2, out);
}

// Round 10
// 241.229 us; speedup vs baseline: 6.1786x; 6.1786x over previous
//
#include <hip/hip_runtime.h>

#define N_NODES 100000
#define N_EDGES 1600000
#define F_INPUT 4
#define HDIM 64
#define G_GRAPHS 1000
#define C_CLS 3

#define NPB 256          // nodes per bucket (power of 2)
#define BSHIFT 8
#define NB 391           // ceil(N_NODES / NPB)
#define CBLK 196         // ceil(N_EDGES / 8192)
#define CSR_CAP 6144     // max edges per bucket staged in LDS
#define EMB_BLOCKS 6250  // N*16 / 256 (4 feats per thread)
#define HIST_BLOCKS 512

typedef __attribute__((ext_vector_type(8))) short bf16x8;
typedef __attribute__((ext_vector_type(4))) float f32x4;

__device__ __forceinline__ unsigned short f2bf(float f) {
    unsigned u = __float_as_uint(f);
    unsigned r = (u + 0x7FFF + ((u >> 16) & 1)) >> 16;  // round-to-nearest-even
    return (unsigned short)r;
}
__device__ __forceinline__ float bflo(unsigned u) {
    return __uint_as_float(u << 16);
}
__device__ __forceinline__ float bfhi(unsigned u) {
    return __uint_as_float(u & 0xFFFF0000u);
}
__device__ __forceinline__ float bf1(unsigned short s) {
    return __uint_as_float(((unsigned)s) << 16);
}

// ---------------- fused: embedding (bf16 out) + bucket histogram ----------------
__global__ __launch_bounds__(256) void k_emb_hist(
    const float* __restrict__ x, const float* __restrict__ w, const float* __restrict__ b,
    unsigned short* __restrict__ h, const int* __restrict__ dst, int* __restrict__ bcnt) {
    __shared__ int s[NB];
    if (blockIdx.x < EMB_BLOCKS) {
        int t = blockIdx.x * 256 + threadIdx.x;   // [0, N*16)
        int n = t >> 4, f0 = (t & 15) * 4;
        const float* xr = x + n * F_INPUT;
        float x0 = xr[0], x1 = xr[1], x2 = xr[2], x3 = xr[3];
        ushort4 o;
        {
            float a0 = b[f0+0] + x0*w[0*HDIM+f0+0] + x1*w[1*HDIM+f0+0] + x2*w[2*HDIM+f0+0] + x3*w[3*HDIM+f0+0];
            float a1 = b[f0+1] + x0*w[0*HDIM+f0+1] + x1*w[1*HDIM+f0+1] + x2*w[2*HDIM+f0+1] + x3*w[3*HDIM+f0+1];
            float a2 = b[f0+2] + x0*w[0*HDIM+f0+2] + x1*w[1*HDIM+f0+2] + x2*w[2*HDIM+f0+2] + x3*w[3*HDIM+f0+2];
            float a3 = b[f0+3] + x0*w[0*HDIM+f0+3] + x1*w[1*HDIM+f0+3] + x2*w[2*HDIM+f0+3] + x3*w[3*HDIM+f0+3];
            o.x = f2bf(a0); o.y = f2bf(a1); o.z = f2bf(a2); o.w = f2bf(a3);
        }
        *(ushort4*)(h + (size_t)n * HDIM + f0) = o;
    } else {
        int bb = blockIdx.x - EMB_BLOCKS;
        for (int i = threadIdx.x; i < NB; i += 256) s[i] = 0;
        __syncthreads();
        for (int e = bb * 256 + threadIdx.x; e < N_EDGES; e += HIST_BLOCKS * 256)
            atomicAdd(&s[dst[e] >> BSHIFT], 1);
        __syncthreads();
        for (int i = threadIdx.x; i < NB; i += 256)
            if (s[i]) atomicAdd(&bcnt[i], s[i]);
    }
}

// ---------------- fused: bucket-offset scan + graph boundaries ----------------
__global__ __launch_bounds__(512) void k_boff_bounds(
    const int* __restrict__ bcnt, int* __restrict__ boff, int* __restrict__ bcur,
    const int* __restrict__ batch, int* __restrict__ goff) {
    if (blockIdx.x == 0) {
        __shared__ int s[512];
        int t = threadIdx.x;
        int v = (t < NB) ? bcnt[t] : 0;
        s[t] = v;
        __syncthreads();
        for (int d = 1; d < 512; d <<= 1) {
            int x2 = (t >= d) ? s[t - d] : 0;
            __syncthreads();
            s[t] += x2;
            __syncthreads();
        }
        int ex = s[t] - v;
        if (t < NB) { boff[t] = ex; bcur[t] = ex; }
        if (t == 0) boff[NB] = N_EDGES;
    } else {
        int n = (blockIdx.x - 1) * 512 + threadIdx.x;
        if (n >= N_NODES) return;
        int bv = batch[n];
        int bp = (n == 0) ? -1 : batch[n - 1];
        for (int g = bp + 1; g <= bv; ++g) goff[g] = n;
        if (n == N_NODES - 1) {
            for (int g = bv + 1; g <= G_GRAPHS; ++g) goff[g] = N_NODES;
        }
    }
}

// ---------------- scatter edges into buckets (packed 8B records) ----------------
// record: x = src | (dloc << 17) ; y = bits of w.  8 edges/thread for long runs.
__global__ __launch_bounds__(1024) void k_bucket(const int* __restrict__ src,
                                                 const int* __restrict__ dst,
                                                 const float* __restrict__ attr,
                                                 int* __restrict__ bcur,
                                                 int2* __restrict__ bbuf) {
    __shared__ int cnt[NB];
    __shared__ int base[NB];
    for (int i = threadIdx.x; i < NB; i += 1024) cnt[i] = 0;
    __syncthreads();
    int e0 = blockIdx.x * 8192;
    int myb[8], myrank[8];
    int2 mypack[8];
#pragma unroll
    for (int k = 0; k < 8; ++k) {
        int e = e0 + k * 1024 + threadIdx.x;
        if (e < N_EDGES) {
            int d = dst[e];
            int b = d >> BSHIFT;
            myb[k] = b;
            myrank[k] = atomicAdd(&cnt[b], 1);
            mypack[k].x = src[e] | ((d & (NPB - 1)) << 17);
            mypack[k].y = __float_as_int(attr[e]);
        } else
            myb[k] = -1;
    }
    __syncthreads();
    for (int i = threadIdx.x; i < NB; i += 1024)
        base[i] = cnt[i] ? atomicAdd(&bcur[i], cnt[i]) : 0;
    __syncthreads();
#pragma unroll
    for (int k = 0; k < 8; ++k)
        if (myb[k] >= 0) bbuf[base[myb[k]] + myrank[k]] = mypack[k];
}

// ---------------- per-bucket CSR finalize (single pass, LDS-staged) ----------------
__global__ __launch_bounds__(256) void k_csr(const int2* __restrict__ bbuf,
                                             const int* __restrict__ boff,
                                             int* __restrict__ off,
                                             float* __restrict__ wsum,
                                             int2* __restrict__ edge2) {
    __shared__ int2 se[CSR_CAP];   // 48 KB
    __shared__ int deg[NPB];
    __shared__ float wsm[NPB];
    __shared__ int loff[NPB];
    __shared__ int sct[256];
    int b = blockIdx.x;
    int lo = boff[b];
    int cnt = boff[b + 1] - lo;
    if (cnt > CSR_CAP) cnt = CSR_CAP;   // statistically impossible; safety clamp
    int t = threadIdx.x;
    deg[t] = 0;
    wsm[t] = 0.f;
    for (int i = t; i < cnt; i += 256) se[i] = bbuf[lo + i];
    __syncthreads();
    for (int i = t; i < cnt; i += 256) {
        int2 p = se[i];
        int dloc = (p.x >> 17) & (NPB - 1);
        atomicAdd(&deg[dloc], 1);
        atomicAdd(&wsm[dloc], __int_as_float(p.y));
    }
    __syncthreads();
    int v = deg[t];
    sct[t] = v;
    __syncthreads();
    for (int d = 1; d < 256; d <<= 1) {
        int x2 = (t >= d) ? sct[t - d] : 0;
        __syncthreads();
        sct[t] += x2;
        __syncthreads();
    }
    int ex = sct[t] - v;
    loff[t] = ex;
    __syncthreads();
    int n = b * NPB + t;
    if (n < N_NODES) { off[n] = lo + ex; wsum[n] = wsm[t]; }
    if (b == NB - 1 && t == 0) off[N_NODES] = N_EDGES;
    deg[t] = 0;  // reuse as cursor
    __syncthreads();
    for (int i = t; i < cnt; i += 256) {
        int2 p = se[i];
        int dloc = (p.x >> 17) & (NPB - 1);
        int r = atomicAdd(&deg[dloc], 1);
        edge2[lo + loff[dloc] + r] = make_int2(p.x & 0x1FFFF, p.y);
    }
}

// ---------------- MFMA fused 3-GEMM (h bf16 in; a bf16, d bf16 out) ----------------
__global__ __launch_bounds__(256) void k_gemm3(
    const unsigned short* __restrict__ h,
    const float* __restrict__ W1, const float* __restrict__ b1,
    const float* __restrict__ W2,
    const float* __restrict__ W3, const float* __restrict__ b3,
    const float* __restrict__ wsum,
    unsigned short* __restrict__ a_out, unsigned short* __restrict__ d_out_) {
    int wave = threadIdx.x >> 6;   // coltile 0..3
    int lane = threadIdx.x & 63;
    int row = lane & 15;
    int kg = lane >> 4;            // k-group 0..3
    int base = blockIdx.x * 64;
    int col = wave * 16 + row;     // output feature

    bf16x8 Bf[3][2];
    const float* Ws[3] = {W1, W2, W3};
#pragma unroll
    for (int m = 0; m < 3; ++m)
#pragma unroll
        for (int hf = 0; hf < 2; ++hf) {
            union { bf16x8 v; unsigned short u[8]; } fr;
#pragma unroll
            for (int j = 0; j < 8; ++j) {
                int k = hf * 32 + kg * 8 + j;
                fr.u[j] = f2bf(Ws[m][k * HDIM + col]);
            }
            Bf[m][hf] = fr.v;
        }

    float bias1 = b1[col];
    float bias3 = b3[col];

    f32x4 acc[3][4];
#pragma unroll
    for (int m = 0; m < 3; ++m)
#pragma unroll
        for (int t = 0; t < 4; ++t) acc[m][t] = (f32x4){0.f, 0.f, 0.f, 0.f};

#pragma unroll
    for (int t = 0; t < 4; ++t) {
        int n = base + t * 16 + row;
        bf16x8 a0, a1;
        if (n < N_NODES) {
            const unsigned short* hr = h + (size_t)n * HDIM;
            a0 = *(const bf16x8*)(hr + kg * 8);
            a1 = *(const bf16x8*)(hr + 32 + kg * 8);
        } else {
            a0 = (bf16x8){0,0,0,0,0,0,0,0};
            a1 = (bf16x8){0,0,0,0,0,0,0,0};
        }
#pragma unroll
        for (int m = 0; m < 3; ++m) {
            acc[m][t] = __builtin_amdgcn_mfma_f32_16x16x32_bf16(a0, Bf[m][0], acc[m][t], 0, 0, 0);
            acc[m][t] = __builtin_amdgcn_mfma_f32_16x16x32_bf16(a1, Bf[m][1], acc[m][t], 0, 0, 0);
        }
    }

#pragma unroll
    for (int t = 0; t < 4; ++t) {
#pragma unroll
        for (int r = 0; r < 4; ++r) {
            int n = base + t * 16 + kg * 4 + r;
            if (n >= N_NODES) continue;
            float ws = wsum[n];
            float av = acc[0][t][r] + bias1;
            float dv = acc[2][t][r] + bias3 - acc[1][t][r] * ws;
            a_out[(size_t)n * HDIM + col] = f2bf(av);
            d_out_[(size_t)n * HDIM + col] = f2bf(dv);
        }
    }
}

// ---------------- CSR aggregate + relu: h = relu(sum_j a[src_j]*w_j + d) ----------------
// 8 slots x 8 lanes; each lane gathers bf16x8 (16B), unroll x4 -> 32 edges/iter.
__global__ __launch_bounds__(256) void k_agg(const int2* __restrict__ edge2,
                                             const int* __restrict__ off,
                                             const unsigned short* __restrict__ a,
                                             const unsigned short* __restrict__ dbuf,
                                             unsigned short* __restrict__ h) {
    int wid = threadIdx.x >> 6;
    int lane = threadIdx.x & 63;
    int slot = lane >> 3;        // 0..7
    int fo = lane & 7;           // feature octet: feats [fo*8, fo*8+8)
    int n = blockIdx.x * 4 + wid;
    if (n >= N_NODES) return;
    int lo = off[n], hi = off[n + 1];

    float acc[8];
#pragma unroll
    for (int q = 0; q < 8; ++q) acc[q] = 0.f;

#define GATHER_ADD(J)                                                        \
    if ((J) < hi) {                                                          \
        int2 p = edge2[(J)];                                                 \
        float w = __int_as_float(p.y);                                       \
        uint4 u = *(const uint4*)(a + (size_t)p.x * HDIM + fo * 8);          \
        acc[0] += bflo(u.x) * w; acc[1] += bfhi(u.x) * w;                    \
        acc[2] += bflo(u.y) * w; acc[3] += bfhi(u.y) * w;                    \
        acc[4] += bflo(u.z) * w; acc[5] += bfhi(u.z) * w;                    \
        acc[6] += bflo(u.w) * w; acc[7] += bfhi(u.w) * w;                    \
    }

    for (int j0 = lo; j0 < hi; j0 += 32) {
        GATHER_ADD(j0 + slot)
        GATHER_ADD(j0 + 8 + slot)
        GATHER_ADD(j0 + 16 + slot)
        GATHER_ADD(j0 + 24 + slot)
    }
#undef GATHER_ADD

#pragma unroll
    for (int m = 8; m <= 32; m <<= 1) {
#pragma unroll
        for (int q = 0; q < 8; ++q) acc[q] += __shfl_xor(acc[q], m);
    }

    if (slot == 0) {
        size_t o = (size_t)n * HDIM + fo * 8;
        uint4 dv = *(const uint4*)(dbuf + o);
        float dd[8] = {bflo(dv.x), bfhi(dv.x), bflo(dv.y), bfhi(dv.y),
                       bflo(dv.z), bfhi(dv.z), bflo(dv.w), bfhi(dv.w)};
        unsigned r[4];
#pragma unroll
        for (int q = 0; q < 4; ++q) {
            unsigned lo16 = f2bf(fmaxf(acc[2 * q] + dd[2 * q], 0.f));
            unsigned hi16 = f2bf(fmaxf(acc[2 * q + 1] + dd[2 * q + 1], 0.f));
            r[q] = lo16 | (hi16 << 16);
        }
        *(uint4*)(h + o) = make_uint4(r[0], r[1], r[2], r[3]);
    }
}

// ---------------- fused mean pool + MLP head: one block per graph ----------------
__global__ __launch_bounds__(128) void k_poolhead(const unsigned short* __restrict__ h,
                                                  const int* __restrict__ goff,
                                                  const float* __restrict__ W1,
                                                  const float* __restrict__ b1,
                                                  const float* __restrict__ W2,
                                                  const float* __restrict__ b2,
                                                  float* __restrict__ out) {
    int g = blockIdx.x;
    __shared__ float part[128];
    __shared__ float sx[HDIM];
    __shared__ float sy[2 * HDIM];
    int t = threadIdx.x;
    int lo = goff[g], hi = goff[g + 1];
    int f = t & 63, half = t >> 6;
    float acc = 0.f;
    for (int n = lo + half; n < hi; n += 2) acc += bf1(h[(size_t)n * HDIM + f]);
    part[t] = acc;
    __syncthreads();
    if (t < HDIM) sx[t] = (part[t] + part[t + 64]) / fmaxf((float)(hi - lo), 1.f);
    __syncthreads();
    float a1 = b1[t];
    for (int k = 0; k < HDIM; ++k) a1 += sx[k] * W1[k * 2 * HDIM + t];
    sy[t] = fmaxf(a1, 0.f);
    __syncthreads();
    if (t < C_CLS) {
        float o = b2[t];
        for (int k = 0; k < 2 * HDIM; ++k) o += sy[k] * W2[k * C_CLS + t];
        out[g * C_CLS + t] = o;
    }
}

extern "C" void kernel_launch(void* const* d_in, const int* in_sizes, int n_in,
                              void* d_out, int out_size, void* d_ws, size_t ws_size,
                              hipStream_t stream) {
    const float* x      = (const float*)d_in[0];
    const int*   ei     = (const int*)d_in[1];
    const float* eattr  = (const float*)d_in[2];
    const int*   batch  = (const int*)d_in[3];
    const float* w_emb  = (const float*)d_in[4];
    const float* b_emb  = (const float*)d_in[5];
    const float* lin1_w = (const float*)d_in[6];
    const float* lin1_b = (const float*)d_in[7];
    const float* lin2_w = (const float*)d_in[8];
    const float* lin3_w = (const float*)d_in[9];
    const float* lin3_b = (const float*)d_in[10];
    const float* mlp_w1 = (const float*)d_in[11];
    const float* mlp_b1 = (const float*)d_in[12];
    const float* mlp_w2 = (const float*)d_in[13];
    const float* mlp_b2 = (const float*)d_in[14];
    float* out = (float*)d_out;

    const int* src = ei;
    const int* dst = ei + N_EDGES;

    const size_t NH = (size_t)N_NODES * HDIM;
    unsigned short* h   = (unsigned short*)d_ws;     // NH bf16
    unsigned short* dbf = h + NH;                    // NH bf16
    unsigned short* abf = dbf + NH;                  // NH bf16
    float* wsum = (float*)(abf + NH);                // N
    int2* edge2 = (int2*)(wsum + N_NODES);           // E
    int2* bbuf  = edge2 + N_EDGES;                   // E
    int* off    = (int*)(bbuf + N_EDGES);            // N+1
    int* bcnt   = off + N_NODES + 1;                 // NB (zeroed)
    int* bcur   = bcnt + NB;                         // NB
    int* boff   = bcur + NB;                         // NB+1
    int* goff   = boff + NB + 1;                     // G+1

    hipMemsetAsync(bcnt, 0, NB * sizeof(int), stream);

    k_emb_hist<<<EMB_BLOCKS + HIST_BLOCKS, 256, 0, stream>>>(x, w_emb, b_emb, h, dst, bcnt);
    k_boff_bounds<<<1 + (N_NODES + 511) / 512, 512, 0, stream>>>(bcnt, boff, bcur, batch, goff);
    k_bucket<<<CBLK, 1024, 0, stream>>>(src, dst, eattr, bcur, bbuf);
    k_csr<<<NB, 256, 0, stream>>>(bbuf, boff, off, wsum, edge2);

    int gemm_blocks = (N_NODES + 63) / 64;
    int agg_blocks = (N_NODES + 3) / 4;

    for (int l = 0; l < 2; ++l) {
        const float* W1 = lin1_w + l * HDIM * HDIM;
        const float* B1 = lin1_b + l * HDIM;
        const float* W2 = lin2_w + l * HDIM * HDIM;
        const float* W3 = lin3_w + l * HDIM * HDIM;
        const float* B3 = lin3_b + l * HDIM;
        k_gemm3<<<gemm_blocks, 256, 0, stream>>>(h, W1, B1, W2, W3, B3, wsum, abf, dbf);
        k_agg<<<agg_blocks, 256, 0, stream>>>(edge2, off, abf, dbf, h);
    }

    k_poolhead<<<G_GRAPHS, 128, 0, stream>>>(h, goff, mlp_w1, mlp_b1, mlp_w2, mlp_b2, out);
}

// Round 11
// 235.348 us; speedup vs baseline: 6.3330x; 1.0250x over previous
//
#include <hip/hip_runtime.h>

#define N_NODES 100000
#define N_EDGES 1600000
#define F_INPUT 4
#define HDIM 64
#define G_GRAPHS 1000
#define C_CLS 3

#define NPB 256          // nodes per bucket (power of 2)
#define BSHIFT 8
#define NB 391           // ceil(N_NODES / NPB)
#define CBLK 98          // ceil(N_EDGES / 16384)
#define CSR_CAP 6144     // max edges per bucket staged in LDS
#define EMB_BLOCKS 6250  // N*16 / 256 (4 feats per thread)
#define HIST_BLOCKS 512
#define BNDS_BLOCKS 391  // ceil(N / 256)

typedef __attribute__((ext_vector_type(8))) short bf16x8;
typedef __attribute__((ext_vector_type(4))) float f32x4;

__device__ __forceinline__ unsigned short f2bf(float f) {
    unsigned u = __float_as_uint(f);
    unsigned r = (u + 0x7FFF + ((u >> 16) & 1)) >> 16;  // round-to-nearest-even
    return (unsigned short)r;
}
__device__ __forceinline__ float bflo(unsigned u) {
    return __uint_as_float(u << 16);
}
__device__ __forceinline__ float bfhi(unsigned u) {
    return __uint_as_float(u & 0xFFFF0000u);
}
__device__ __forceinline__ float bf1(unsigned short s) {
    return __uint_as_float(((unsigned)s) << 16);
}

// ---------------- fused: embedding (bf16 out) + bucket histogram + graph bounds ----------------
__global__ __launch_bounds__(256) void k_emb_hist(
    const float* __restrict__ x, const float* __restrict__ w, const float* __restrict__ b,
    unsigned short* __restrict__ h, const int* __restrict__ dst, int* __restrict__ bcnt,
    const int* __restrict__ batch, int* __restrict__ goff) {
    __shared__ int s[NB];
    if (blockIdx.x < EMB_BLOCKS) {
        int t = blockIdx.x * 256 + threadIdx.x;   // [0, N*16)
        int n = t >> 4, f0 = (t & 15) * 4;
        const float* xr = x + n * F_INPUT;
        float x0 = xr[0], x1 = xr[1], x2 = xr[2], x3 = xr[3];
        ushort4 o;
        {
            float a0 = b[f0+0] + x0*w[0*HDIM+f0+0] + x1*w[1*HDIM+f0+0] + x2*w[2*HDIM+f0+0] + x3*w[3*HDIM+f0+0];
            float a1 = b[f0+1] + x0*w[0*HDIM+f0+1] + x1*w[1*HDIM+f0+1] + x2*w[2*HDIM+f0+1] + x3*w[3*HDIM+f0+1];
            float a2 = b[f0+2] + x0*w[0*HDIM+f0+2] + x1*w[1*HDIM+f0+2] + x2*w[2*HDIM+f0+2] + x3*w[3*HDIM+f0+2];
            float a3 = b[f0+3] + x0*w[0*HDIM+f0+3] + x1*w[1*HDIM+f0+3] + x2*w[2*HDIM+f0+3] + x3*w[3*HDIM+f0+3];
            o.x = f2bf(a0); o.y = f2bf(a1); o.z = f2bf(a2); o.w = f2bf(a3);
        }
        *(ushort4*)(h + (size_t)n * HDIM + f0) = o;
    } else if (blockIdx.x < EMB_BLOCKS + HIST_BLOCKS) {
        int bb = blockIdx.x - EMB_BLOCKS;
        for (int i = threadIdx.x; i < NB; i += 256) s[i] = 0;
        __syncthreads();
        for (int e = bb * 256 + threadIdx.x; e < N_EDGES; e += HIST_BLOCKS * 256)
            atomicAdd(&s[dst[e] >> BSHIFT], 1);
        __syncthreads();
        for (int i = threadIdx.x; i < NB; i += 256)
            if (s[i]) atomicAdd(&bcnt[i], s[i]);
    } else {
        int n = (blockIdx.x - EMB_BLOCKS - HIST_BLOCKS) * 256 + threadIdx.x;
        if (n >= N_NODES) return;
        int bv = batch[n];
        int bp = (n == 0) ? -1 : batch[n - 1];
        for (int g = bp + 1; g <= bv; ++g) goff[g] = n;
        if (n == N_NODES - 1) {
            for (int g = bv + 1; g <= G_GRAPHS; ++g) goff[g] = N_NODES;
        }
    }
}

// ---------------- bucket-offset scan (1 block) ----------------
__global__ __launch_bounds__(512) void k_boff(
    const int* __restrict__ bcnt, int* __restrict__ boff, int* __restrict__ bcur) {
    __shared__ int s[512];
    int t = threadIdx.x;
    int v = (t < NB) ? bcnt[t] : 0;
    s[t] = v;
    __syncthreads();
    for (int d = 1; d < 512; d <<= 1) {
        int x2 = (t >= d) ? s[t - d] : 0;
        __syncthreads();
        s[t] += x2;
        __syncthreads();
    }
    int ex = s[t] - v;
    if (t < NB) { boff[t] = ex; bcur[t] = ex; }
    if (t == 0) boff[NB] = N_EDGES;
}

// ---------------- scatter edges into buckets (packed 8B records) ----------------
// record: x = src | (dloc << 17) ; y = bits of w.  16 edges/thread for long runs.
__global__ __launch_bounds__(1024) void k_bucket(const int* __restrict__ src,
                                                 const int* __restrict__ dst,
                                                 const float* __restrict__ attr,
                                                 int* __restrict__ bcur,
                                                 int2* __restrict__ bbuf) {
    __shared__ int cnt[NB];
    __shared__ int base[NB];
    for (int i = threadIdx.x; i < NB; i += 1024) cnt[i] = 0;
    __syncthreads();
    int e0 = blockIdx.x * 16384;
    int myb[16], myrank[16];
    int2 mypack[16];
#pragma unroll
    for (int k = 0; k < 16; ++k) {
        int e = e0 + k * 1024 + threadIdx.x;
        if (e < N_EDGES) {
            int d = dst[e];
            int b = d >> BSHIFT;
            myb[k] = b;
            myrank[k] = atomicAdd(&cnt[b], 1);
            mypack[k].x = src[e] | ((d & (NPB - 1)) << 17);
            mypack[k].y = __float_as_int(attr[e]);
        } else
            myb[k] = -1;
    }
    __syncthreads();
    for (int i = threadIdx.x; i < NB; i += 1024)
        base[i] = cnt[i] ? atomicAdd(&bcur[i], cnt[i]) : 0;
    __syncthreads();
#pragma unroll
    for (int k = 0; k < 16; ++k)
        if (myb[k] >= 0) bbuf[base[myb[k]] + myrank[k]] = mypack[k];
}

// ---------------- per-bucket CSR finalize (single pass, LDS-staged) ----------------
__global__ __launch_bounds__(256) void k_csr(const int2* __restrict__ bbuf,
                                             const int* __restrict__ boff,
                                             int* __restrict__ off,
                                             float* __restrict__ wsum,
                                             int2* __restrict__ edge2) {
    __shared__ int2 se[CSR_CAP];   // 48 KB
    __shared__ int deg[NPB];
    __shared__ float wsm[NPB];
    __shared__ int loff[NPB];
    __shared__ int sct[256];
    int b = blockIdx.x;
    int lo = boff[b];
    int cnt = boff[b + 1] - lo;
    if (cnt > CSR_CAP) cnt = CSR_CAP;   // statistically impossible; safety clamp
    int t = threadIdx.x;
    deg[t] = 0;
    wsm[t] = 0.f;
    for (int i = t; i < cnt; i += 256) se[i] = bbuf[lo + i];
    __syncthreads();
    for (int i = t; i < cnt; i += 256) {
        int2 p = se[i];
        int dloc = (p.x >> 17) & (NPB - 1);
        atomicAdd(&deg[dloc], 1);
        atomicAdd(&wsm[dloc], __int_as_float(p.y));
    }
    __syncthreads();
    int v = deg[t];
    sct[t] = v;
    __syncthreads();
    for (int d = 1; d < 256; d <<= 1) {
        int x2 = (t >= d) ? sct[t - d] : 0;
        __syncthreads();
        sct[t] += x2;
        __syncthreads();
    }
    int ex = sct[t] - v;
    loff[t] = ex;
    __syncthreads();
    int n = b * NPB + t;
    if (n < N_NODES) { off[n] = lo + ex; wsum[n] = wsm[t]; }
    if (b == NB - 1 && t == 0) off[N_NODES] = N_EDGES;
    deg[t] = 0;  // reuse as cursor
    __syncthreads();
    for (int i = t; i < cnt; i += 256) {
        int2 p = se[i];
        int dloc = (p.x >> 17) & (NPB - 1);
        int r = atomicAdd(&deg[dloc], 1);
        edge2[lo + loff[dloc] + r] = make_int2(p.x & 0x1FFFF, p.y);
    }
}

// ---------------- MFMA fused 3-GEMM (h bf16 in; a bf16, d bf16 out) ----------------
__global__ __launch_bounds__(256) void k_gemm3(
    const unsigned short* __restrict__ h,
    const float* __restrict__ W1, const float* __restrict__ b1,
    const float* __restrict__ W2,
    const float* __restrict__ W3, const float* __restrict__ b3,
    const float* __restrict__ wsum,
    unsigned short* __restrict__ a_out, unsigned short* __restrict__ d_out_) {
    int wave = threadIdx.x >> 6;   // coltile 0..3
    int lane = threadIdx.x & 63;
    int row = lane & 15;
    int kg = lane >> 4;            // k-group 0..3
    int base = blockIdx.x * 64;
    int col = wave * 16 + row;     // output feature

    bf16x8 Bf[3][2];
    const float* Ws[3] = {W1, W2, W3};
#pragma unroll
    for (int m = 0; m < 3; ++m)
#pragma unroll
        for (int hf = 0; hf < 2; ++hf) {
            union { bf16x8 v; unsigned short u[8]; } fr;
#pragma unroll
            for (int j = 0; j < 8; ++j) {
                int k = hf * 32 + kg * 8 + j;
                fr.u[j] = f2bf(Ws[m][k * HDIM + col]);
            }
            Bf[m][hf] = fr.v;
        }

    float bias1 = b1[col];
    float bias3 = b3[col];

    f32x4 acc[3][4];
#pragma unroll
    for (int m = 0; m < 3; ++m)
#pragma unroll
        for (int t = 0; t < 4; ++t) acc[m][t] = (f32x4){0.f, 0.f, 0.f, 0.f};

#pragma unroll
    for (int t = 0; t < 4; ++t) {
        int n = base + t * 16 + row;
        bf16x8 a0, a1;
        if (n < N_NODES) {
            const unsigned short* hr = h + (size_t)n * HDIM;
            a0 = *(const bf16x8*)(hr + kg * 8);
            a1 = *(const bf16x8*)(hr + 32 + kg * 8);
        } else {
            a0 = (bf16x8){0,0,0,0,0,0,0,0};
            a1 = (bf16x8){0,0,0,0,0,0,0,0};
        }
#pragma unroll
        for (int m = 0; m < 3; ++m) {
            acc[m][t] = __builtin_amdgcn_mfma_f32_16x16x32_bf16(a0, Bf[m][0], acc[m][t], 0, 0, 0);
            acc[m][t] = __builtin_amdgcn_mfma_f32_16x16x32_bf16(a1, Bf[m][1], acc[m][t], 0, 0, 0);
        }
    }

#pragma unroll
    for (int t = 0; t < 4; ++t) {
#pragma unroll
        for (int r = 0; r < 4; ++r) {
            int n = base + t * 16 + kg * 4 + r;
            if (n >= N_NODES) continue;
            float ws = wsum[n];
            float av = acc[0][t][r] + bias1;
            float dv = acc[2][t][r] + bias3 - acc[1][t][r] * ws;
            a_out[(size_t)n * HDIM + col] = f2bf(av);
            d_out_[(size_t)n * HDIM + col] = f2bf(dv);
        }
    }
}

// ---------------- CSR aggregate + relu: h = relu(sum_j a[src_j]*w_j + d) ----------------
// 8 slots x 8 lanes; each lane gathers bf16x8 (16B), unroll x4 -> 32 edges/iter.
__global__ __launch_bounds__(256) void k_agg(const int2* __restrict__ edge2,
                                             const int* __restrict__ off,
                                             const unsigned short* __restrict__ a,
                                             const unsigned short* __restrict__ dbuf,
                                             unsigned short* __restrict__ h) {
    int wid = threadIdx.x >> 6;
    int lane = threadIdx.x & 63;
    int slot = lane >> 3;        // 0..7
    int fo = lane & 7;           // feature octet: feats [fo*8, fo*8+8)
    int n = blockIdx.x * 4 + wid;
    if (n >= N_NODES) return;
    int lo = off[n], hi = off[n + 1];

    float acc[8];
#pragma unroll
    for (int q = 0; q < 8; ++q) acc[q] = 0.f;

#define GATHER_ADD(J)                                                        \
    if ((J) < hi) {                                                          \
        int2 p = edge2[(J)];                                                 \
        float w = __int_as_float(p.y);                                       \
        uint4 u = *(const uint4*)(a + (size_t)p.x * HDIM + fo * 8);          \
        acc[0] += bflo(u.x) * w; acc[1] += bfhi(u.x) * w;                    \
        acc[2] += bflo(u.y) * w; acc[3] += bfhi(u.y) * w;                    \
        acc[4] += bflo(u.z) * w; acc[5] += bfhi(u.z) * w;                    \
        acc[6] += bflo(u.w) * w; acc[7] += bfhi(u.w) * w;                    \
    }

    for (int j0 = lo; j0 < hi; j0 += 32) {
        GATHER_ADD(j0 + slot)
        GATHER_ADD(j0 + 8 + slot)
        GATHER_ADD(j0 + 16 + slot)
        GATHER_ADD(j0 + 24 + slot)
    }
#undef GATHER_ADD

#pragma unroll
    for (int m = 8; m <= 32; m <<= 1) {
#pragma unroll
        for (int q = 0; q < 8; ++q) acc[q] += __shfl_xor(acc[q], m);
    }

    if (slot == 0) {
        size_t o = (size_t)n * HDIM + fo * 8;
        uint4 dv = *(const uint4*)(dbuf + o);
        float dd[8] = {bflo(dv.x), bfhi(dv.x), bflo(dv.y), bfhi(dv.y),
                       bflo(dv.z), bfhi(dv.z), bflo(dv.w), bfhi(dv.w)};
        unsigned r[4];
#pragma unroll
        for (int q = 0; q < 4; ++q) {
            unsigned lo16 = f2bf(fmaxf(acc[2 * q] + dd[2 * q], 0.f));
            unsigned hi16 = f2bf(fmaxf(acc[2 * q + 1] + dd[2 * q + 1], 0.f));
            r[q] = lo16 | (hi16 << 16);
        }
        *(uint4*)(h + o) = make_uint4(r[0], r[1], r[2], r[3]);
    }
}

// ---------------- fused mean pool + MLP head: one block per graph, 256 thr ----------------
__global__ __launch_bounds__(256) void k_poolhead(const unsigned short* __restrict__ h,
                                                  const int* __restrict__ goff,
                                                  const float* __restrict__ W1,
                                                  const float* __restrict__ b1,
                                                  const float* __restrict__ W2,
                                                  const float* __restrict__ b2,
                                                  float* __restrict__ out) {
    int g = blockIdx.x;
    __shared__ float part[256];
    __shared__ float sx[HDIM];
    __shared__ float sy[2 * HDIM];
    int t = threadIdx.x;
    int lo = goff[g], hi = goff[g + 1];
    int f = t & 63, quarter = t >> 6;
    float acc = 0.f;
    for (int n = lo + quarter; n < hi; n += 4) acc += bf1(h[(size_t)n * HDIM + f]);
    part[t] = acc;
    __syncthreads();
    if (t < HDIM)
        sx[t] = (part[t] + part[t + 64] + part[t + 128] + part[t + 192]) /
                fmaxf((float)(hi - lo), 1.f);
    __syncthreads();
    if (t < 2 * HDIM) {
        float a1 = b1[t];
        for (int k = 0; k < HDIM; ++k) a1 += sx[k] * W1[k * 2 * HDIM + t];
        sy[t] = fmaxf(a1, 0.f);
    }
    __syncthreads();
    if (t < C_CLS) {
        float o = b2[t];
        for (int k = 0; k < 2 * HDIM; ++k) o += sy[k] * W2[k * C_CLS + t];
        out[g * C_CLS + t] = o;
    }
}

extern "C" void kernel_launch(void* const* d_in, const int* in_sizes, int n_in,
                              void* d_out, int out_size, void* d_ws, size_t ws_size,
                              hipStream_t stream) {
    const float* x      = (const float*)d_in[0];
    const int*   ei     = (const int*)d_in[1];
    const float* eattr  = (const float*)d_in[2];
    const int*   batch  = (const int*)d_in[3];
    const float* w_emb  = (const float*)d_in[4];
    const float* b_emb  = (const float*)d_in[5];
    const float* lin1_w = (const float*)d_in[6];
    const float* lin1_b = (const float*)d_in[7];
    const float* lin2_w = (const float*)d_in[8];
    const float* lin3_w = (const float*)d_in[9];
    const float* lin3_b = (const float*)d_in[10];
    const float* mlp_w1 = (const float*)d_in[11];
    const float* mlp_b1 = (const float*)d_in[12];
    const float* mlp_w2 = (const float*)d_in[13];
    const float* mlp_b2 = (const float*)d_in[14];
    float* out = (float*)d_out;

    const int* src = ei;
    const int* dst = ei + N_EDGES;

    const size_t NH = (size_t)N_NODES * HDIM;
    unsigned short* h   = (unsigned short*)d_ws;     // NH bf16
    unsigned short* dbf = h + NH;                    // NH bf16
    unsigned short* abf = dbf + NH;                  // NH bf16
    float* wsum = (float*)(abf + NH);                // N
    int2* edge2 = (int2*)(wsum + N_NODES);           // E
    int2* bbuf  = edge2 + N_EDGES;                   // E
    int* off    = (int*)(bbuf + N_EDGES);            // N+1
    int* bcnt   = off + N_NODES + 1;                 // NB (zeroed)
    int* bcur   = bcnt + NB;                         // NB
    int* boff   = bcur + NB;                         // NB+1
    int* goff   = boff + NB + 1;                     // G+1

    hipMemsetAsync(bcnt, 0, NB * sizeof(int), stream);

    k_emb_hist<<<EMB_BLOCKS + HIST_BLOCKS + BNDS_BLOCKS, 256, 0, stream>>>(
        x, w_emb, b_emb, h, dst, bcnt, batch, goff);
    k_boff<<<1, 512, 0, stream>>>(bcnt, boff, bcur);
    k_bucket<<<CBLK, 1024, 0, stream>>>(src, dst, eattr, bcur, bbuf);
    k_csr<<<NB, 256, 0, stream>>>(bbuf, boff, off, wsum, edge2);

    int gemm_blocks = (N_NODES + 63) / 64;
    int agg_blocks = (N_NODES + 3) / 4;

    for (int l = 0; l < 2; ++l) {
        const float* W1 = lin1_w + l * HDIM * HDIM;
        const float* B1 = lin1_b + l * HDIM;
        const float* W2 = lin2_w + l * HDIM * HDIM;
        const float* W3 = lin3_w + l * HDIM * HDIM;
        const float* B3 = lin3_b + l * HDIM;
        k_gemm3<<<gemm_blocks, 256, 0, stream>>>(h, W1, B1, W2, W3, B3, wsum, abf, dbf);
        k_agg<<<agg_blocks, 256, 0, stream>>>(edge2, off, abf, dbf, h);
    }

    k_poolhead<<<G_GRAPHS, 256, 0, stream>>>(h, goff, mlp_w1, mlp_b1, mlp_w2, mlp_b2, out);
}

// Round 12
// 231.325 us; speedup vs baseline: 6.4431x; 1.0174x over previous
//
#include <hip/hip_runtime.h>

#define N_NODES 100000
#define N_EDGES 1600000
#define F_INPUT 4
#define HDIM 64
#define G_GRAPHS 1000
#define C_CLS 3

#define NPB 256          // nodes per bucket (power of 2)
#define BSHIFT 8
#define NB 391           // ceil(N_NODES / NPB)
#define CBLK 98          // ceil(N_EDGES / 16384)
#define CSR_CAP 6144     // max edges per bucket staged in LDS
#define HIST_BLOCKS 512
#define BNDS_BLOCKS 391  // ceil(N / 256)

typedef __attribute__((ext_vector_type(8))) short bf16x8;
typedef __attribute__((ext_vector_type(4))) float f32x4;

__device__ __forceinline__ unsigned short f2bf(float f) {
    unsigned u = __float_as_uint(f);
    unsigned r = (u + 0x7FFF + ((u >> 16) & 1)) >> 16;  // round-to-nearest-even
    return (unsigned short)r;
}
__device__ __forceinline__ float bflo(unsigned u) {
    return __uint_as_float(u << 16);
}
__device__ __forceinline__ float bfhi(unsigned u) {
    return __uint_as_float(u & 0xFFFF0000u);
}
__device__ __forceinline__ float bf1(unsigned short s) {
    return __uint_as_float(((unsigned)s) << 16);
}

// ---------------- W' = W_emb @ W_l ; b' = b_emb @ W_l + b_l  (layer 0 folding) ----------------
// wp: [3][4][64] fp32 ; bp: [3][64] fp32
__global__ __launch_bounds__(256) void k_prew(
    const float* __restrict__ w_emb, const float* __restrict__ b_emb,
    const float* __restrict__ lin1_w, const float* __restrict__ lin1_b,
    const float* __restrict__ lin2_w,
    const float* __restrict__ lin3_w, const float* __restrict__ lin3_b,
    float* __restrict__ wp, float* __restrict__ bp) {
    int t = threadIdx.x;       // 256 = 4 * 64
    int k = t >> 6, f = t & 63;
    const float* Ws[3] = {lin1_w, lin2_w, lin3_w};
#pragma unroll
    for (int m = 0; m < 3; ++m) {
        float s = 0.f;
        for (int j = 0; j < HDIM; ++j) s += w_emb[k * HDIM + j] * Ws[m][j * HDIM + f];
        wp[m * 256 + k * HDIM + f] = s;
    }
    if (t < HDIM) {
#pragma unroll
        for (int m = 0; m < 3; ++m) {
            float s = 0.f;
            for (int j = 0; j < HDIM; ++j) s += b_emb[j] * Ws[m][j * HDIM + t];
            if (m == 0) s += lin1_b[t];
            if (m == 2) s += lin3_b[t];
            bp[m * HDIM + t] = s;
        }
    }
}

// ---------------- fused: bucket histogram + graph bounds ----------------
__global__ __launch_bounds__(256) void k_hist_bounds(
    const int* __restrict__ dst, int* __restrict__ bcnt,
    const int* __restrict__ batch, int* __restrict__ goff) {
    __shared__ int s[NB];
    if (blockIdx.x < HIST_BLOCKS) {
        int bb = blockIdx.x;
        for (int i = threadIdx.x; i < NB; i += 256) s[i] = 0;
        __syncthreads();
        for (int e = bb * 256 + threadIdx.x; e < N_EDGES; e += HIST_BLOCKS * 256)
            atomicAdd(&s[dst[e] >> BSHIFT], 1);
        __syncthreads();
        for (int i = threadIdx.x; i < NB; i += 256)
            if (s[i]) atomicAdd(&bcnt[i], s[i]);
    } else {
        int n = (blockIdx.x - HIST_BLOCKS) * 256 + threadIdx.x;
        if (n >= N_NODES) return;
        int bv = batch[n];
        int bp_ = (n == 0) ? -1 : batch[n - 1];
        for (int g = bp_ + 1; g <= bv; ++g) goff[g] = n;
        if (n == N_NODES - 1) {
            for (int g = bv + 1; g <= G_GRAPHS; ++g) goff[g] = N_NODES;
        }
    }
}

// ---------------- bucket-offset scan (1 block) ----------------
__global__ __launch_bounds__(512) void k_boff(
    const int* __restrict__ bcnt, int* __restrict__ boff, int* __restrict__ bcur) {
    __shared__ int s[512];
    int t = threadIdx.x;
    int v = (t < NB) ? bcnt[t] : 0;
    s[t] = v;
    __syncthreads();
    for (int d = 1; d < 512; d <<= 1) {
        int x2 = (t >= d) ? s[t - d] : 0;
        __syncthreads();
        s[t] += x2;
        __syncthreads();
    }
    int ex = s[t] - v;
    if (t < NB) { boff[t] = ex; bcur[t] = ex; }
    if (t == 0) boff[NB] = N_EDGES;
}

// ---------------- scatter edges into buckets (packed 8B records) ----------------
__global__ __launch_bounds__(1024) void k_bucket(const int* __restrict__ src,
                                                 const int* __restrict__ dst,
                                                 const float* __restrict__ attr,
                                                 int* __restrict__ bcur,
                                                 int2* __restrict__ bbuf) {
    __shared__ int cnt[NB];
    __shared__ int base[NB];
    for (int i = threadIdx.x; i < NB; i += 1024) cnt[i] = 0;
    __syncthreads();
    int e0 = blockIdx.x * 16384;
    int myb[16], myrank[16];
    int2 mypack[16];
#pragma unroll
    for (int k = 0; k < 16; ++k) {
        int e = e0 + k * 1024 + threadIdx.x;
        if (e < N_EDGES) {
            int d = dst[e];
            int b = d >> BSHIFT;
            myb[k] = b;
            myrank[k] = atomicAdd(&cnt[b], 1);
            mypack[k].x = src[e] | ((d & (NPB - 1)) << 17);
            mypack[k].y = __float_as_int(attr[e]);
        } else
            myb[k] = -1;
    }
    __syncthreads();
    for (int i = threadIdx.x; i < NB; i += 1024)
        base[i] = cnt[i] ? atomicAdd(&bcur[i], cnt[i]) : 0;
    __syncthreads();
#pragma unroll
    for (int k = 0; k < 16; ++k)
        if (myb[k] >= 0) bbuf[base[myb[k]] + myrank[k]] = mypack[k];
}

// ---------------- per-bucket CSR finalize (single pass, LDS-staged) ----------------
__global__ __launch_bounds__(256) void k_csr(const int2* __restrict__ bbuf,
                                             const int* __restrict__ boff,
                                             int* __restrict__ off,
                                             float* __restrict__ wsum,
                                             int2* __restrict__ edge2) {
    __shared__ int2 se[CSR_CAP];   // 48 KB
    __shared__ int deg[NPB];
    __shared__ float wsm[NPB];
    __shared__ int loff[NPB];
    __shared__ int sct[256];
    int b = blockIdx.x;
    int lo = boff[b];
    int cnt = boff[b + 1] - lo;
    if (cnt > CSR_CAP) cnt = CSR_CAP;   // statistically impossible; safety clamp
    int t = threadIdx.x;
    deg[t] = 0;
    wsm[t] = 0.f;
    for (int i = t; i < cnt; i += 256) se[i] = bbuf[lo + i];
    __syncthreads();
    for (int i = t; i < cnt; i += 256) {
        int2 p = se[i];
        int dloc = (p.x >> 17) & (NPB - 1);
        atomicAdd(&deg[dloc], 1);
        atomicAdd(&wsm[dloc], __int_as_float(p.y));
    }
    __syncthreads();
    int v = deg[t];
    sct[t] = v;
    __syncthreads();
    for (int d = 1; d < 256; d <<= 1) {
        int x2 = (t >= d) ? sct[t - d] : 0;
        __syncthreads();
        sct[t] += x2;
        __syncthreads();
    }
    int ex = sct[t] - v;
    loff[t] = ex;
    __syncthreads();
    int n = b * NPB + t;
    if (n < N_NODES) { off[n] = lo + ex; wsum[n] = wsm[t]; }
    if (b == NB - 1 && t == 0) off[N_NODES] = N_EDGES;
    deg[t] = 0;  // reuse as cursor
    __syncthreads();
    for (int i = t; i < cnt; i += 256) {
        int2 p = se[i];
        int dloc = (p.x >> 17) & (NPB - 1);
        int r = atomicAdd(&deg[dloc], 1);
        edge2[lo + loff[dloc] + r] = make_int2(p.x & 0x1FFFF, p.y);
    }
}

// ---------------- layer-0 3-GEMM direct from x (K=4 via folded weights) ----------------
// a0 = x@W1' + b1' ; d0 = x@W3' + b3' - (x@W2' + b2')*wsum
__global__ __launch_bounds__(256) void k_gemm1st(
    const float* __restrict__ x, const float* __restrict__ wp,
    const float* __restrict__ bp, const float* __restrict__ wsum,
    unsigned short* __restrict__ a_out, unsigned short* __restrict__ d_out_) {
    int wave = threadIdx.x >> 6;
    int lane = threadIdx.x & 63;
    int row = lane & 15;
    int kg = lane >> 4;
    int base = blockIdx.x * 64;
    int col = wave * 16 + row;

    bf16x8 Bf[3];
#pragma unroll
    for (int m = 0; m < 3; ++m) {
        union { bf16x8 v; unsigned short u[8]; } fr;
#pragma unroll
        for (int j = 0; j < 8; ++j)
            fr.u[j] = (kg == 0 && j < F_INPUT) ? f2bf(wp[m * 256 + j * HDIM + col]) : 0;
        Bf[m] = fr.v;
    }
    float bias1 = bp[col], bias2 = bp[HDIM + col], bias3 = bp[2 * HDIM + col];

    f32x4 acc[3][4];
#pragma unroll
    for (int m = 0; m < 3; ++m)
#pragma unroll
        for (int t = 0; t < 4; ++t) acc[m][t] = (f32x4){0.f, 0.f, 0.f, 0.f};

#pragma unroll
    for (int t = 0; t < 4; ++t) {
        int n = base + t * 16 + row;
        union { bf16x8 v; unsigned short u[8]; } af;
#pragma unroll
        for (int j = 0; j < 8; ++j) af.u[j] = 0;
        if (kg == 0 && n < N_NODES) {
            float4 xv = *(const float4*)(x + (size_t)n * F_INPUT);
            af.u[0] = f2bf(xv.x); af.u[1] = f2bf(xv.y);
            af.u[2] = f2bf(xv.z); af.u[3] = f2bf(xv.w);
        }
#pragma unroll
        for (int m = 0; m < 3; ++m)
            acc[m][t] = __builtin_amdgcn_mfma_f32_16x16x32_bf16(af.v, Bf[m], acc[m][t], 0, 0, 0);
    }

#pragma unroll
    for (int t = 0; t < 4; ++t) {
#pragma unroll
        for (int r = 0; r < 4; ++r) {
            int n = base + t * 16 + kg * 4 + r;
            if (n >= N_NODES) continue;
            float ws = wsum[n];
            float av = acc[0][t][r] + bias1;
            float dv = acc[2][t][r] + bias3 - (acc[1][t][r] + bias2) * ws;
            a_out[(size_t)n * HDIM + col] = f2bf(av);
            d_out_[(size_t)n * HDIM + col] = f2bf(dv);
        }
    }
}

// ---------------- fused: CSR aggregate (layer 0) + 3-GEMM (layer 1) ----------------
// Block = 16 nodes, 4 waves. Phase A: each wave aggregates 4 nodes -> h1 into LDS.
// Phase B: wave w = coltile w; A-frags from LDS; 6 MFMAs; writes a1,d1.
__global__ __launch_bounds__(256) void k_aggemm(
    const int2* __restrict__ edge2, const int* __restrict__ off,
    const unsigned short* __restrict__ a, const unsigned short* __restrict__ dbuf,
    const float* __restrict__ W1, const float* __restrict__ b1,
    const float* __restrict__ W2,
    const float* __restrict__ W3, const float* __restrict__ b3,
    const float* __restrict__ wsum,
    unsigned short* __restrict__ a_out, unsigned short* __restrict__ d_out_) {
    __shared__ unsigned short ht[16 * 72];   // stride 72 shorts = 144 B
    int tid = threadIdx.x;
    int wid = tid >> 6, lane = tid & 63;
    int slot = lane >> 3, fo = lane & 7;
    int base = blockIdx.x * 16;

    // ---- phase A: aggregate 4 nodes per wave ----
    for (int nn = 0; nn < 4; ++nn) {
        int n = base + wid * 4 + nn;
        int lo = off[n], hi = off[n + 1];
        float acc[8];
#pragma unroll
        for (int q = 0; q < 8; ++q) acc[q] = 0.f;

#define GATHER_ADD(J)                                                        \
    if ((J) < hi) {                                                          \
        int2 p = edge2[(J)];                                                 \
        float w = __int_as_float(p.y);                                       \
        uint4 u = *(const uint4*)(a + (size_t)p.x * HDIM + fo * 8);          \
        acc[0] += bflo(u.x) * w; acc[1] += bfhi(u.x) * w;                    \
        acc[2] += bflo(u.y) * w; acc[3] += bfhi(u.y) * w;                    \
        acc[4] += bflo(u.z) * w; acc[5] += bfhi(u.z) * w;                    \
        acc[6] += bflo(u.w) * w; acc[7] += bfhi(u.w) * w;                    \
    }
        for (int j0 = lo; j0 < hi; j0 += 32) {
            GATHER_ADD(j0 + slot)
            GATHER_ADD(j0 + 8 + slot)
            GATHER_ADD(j0 + 16 + slot)
            GATHER_ADD(j0 + 24 + slot)
        }
#undef GATHER_ADD

#pragma unroll
        for (int m = 8; m <= 32; m <<= 1) {
#pragma unroll
            for (int q = 0; q < 8; ++q) acc[q] += __shfl_xor(acc[q], m);
        }

        if (slot == 0) {
            size_t o = (size_t)n * HDIM + fo * 8;
            uint4 dv = *(const uint4*)(dbuf + o);
            float dd[8] = {bflo(dv.x), bfhi(dv.x), bflo(dv.y), bfhi(dv.y),
                           bflo(dv.z), bfhi(dv.z), bflo(dv.w), bfhi(dv.w)};
            unsigned r[4];
#pragma unroll
            for (int q = 0; q < 4; ++q) {
                unsigned lo16 = f2bf(fmaxf(acc[2 * q] + dd[2 * q], 0.f));
                unsigned hi16 = f2bf(fmaxf(acc[2 * q + 1] + dd[2 * q + 1], 0.f));
                r[q] = lo16 | (hi16 << 16);
            }
            *(uint4*)(&ht[(wid * 4 + nn) * 72 + fo * 8]) = make_uint4(r[0], r[1], r[2], r[3]);
        }
    }
    __syncthreads();

    // ---- phase B: 3-GEMM on the 16-node tile ----
    int row = lane & 15, kg = lane >> 4;
    int col = wid * 16 + row;

    bf16x8 Bf[3][2];
    const float* Ws[3] = {W1, W2, W3};
#pragma unroll
    for (int m = 0; m < 3; ++m)
#pragma unroll
        for (int hf = 0; hf < 2; ++hf) {
            union { bf16x8 v; unsigned short u[8]; } fr;
#pragma unroll
            for (int j = 0; j < 8; ++j) {
                int k = hf * 32 + kg * 8 + j;
                fr.u[j] = f2bf(Ws[m][k * HDIM + col]);
            }
            Bf[m][hf] = fr.v;
        }

    bf16x8 a0 = *(const bf16x8*)(&ht[row * 72 + kg * 8]);
    bf16x8 a1 = *(const bf16x8*)(&ht[row * 72 + 32 + kg * 8]);

    f32x4 acc3[3];
#pragma unroll
    for (int m = 0; m < 3; ++m) {
        acc3[m] = (f32x4){0.f, 0.f, 0.f, 0.f};
        acc3[m] = __builtin_amdgcn_mfma_f32_16x16x32_bf16(a0, Bf[m][0], acc3[m], 0, 0, 0);
        acc3[m] = __builtin_amdgcn_mfma_f32_16x16x32_bf16(a1, Bf[m][1], acc3[m], 0, 0, 0);
    }

    float bias1 = b1[col];
    float bias3 = b3[col];
#pragma unroll
    for (int r = 0; r < 4; ++r) {
        int n = base + kg * 4 + r;
        float ws = wsum[n];
        float av = acc3[0][r] + bias1;
        float dv = acc3[2][r] + bias3 - acc3[1][r] * ws;
        a_out[(size_t)n * HDIM + col] = f2bf(av);
        d_out_[(size_t)n * HDIM + col] = f2bf(dv);
    }
}

// ---------------- CSR aggregate + relu (final layer): h2 = relu(sum + d) ----------------
__global__ __launch_bounds__(256) void k_agg(const int2* __restrict__ edge2,
                                             const int* __restrict__ off,
                                             const unsigned short* __restrict__ a,
                                             const unsigned short* __restrict__ dbuf,
                                             unsigned short* __restrict__ h) {
    int wid = threadIdx.x >> 6;
    int lane = threadIdx.x & 63;
    int slot = lane >> 3;
    int fo = lane & 7;
    int n = blockIdx.x * 4 + wid;
    if (n >= N_NODES) return;
    int lo = off[n], hi = off[n + 1];

    float acc[8];
#pragma unroll
    for (int q = 0; q < 8; ++q) acc[q] = 0.f;

#define GATHER_ADD(J)                                                        \
    if ((J) < hi) {                                                          \
        int2 p = edge2[(J)];                                                 \
        float w = __int_as_float(p.y);                                       \
        uint4 u = *(const uint4*)(a + (size_t)p.x * HDIM + fo * 8);          \
        acc[0] += bflo(u.x) * w; acc[1] += bfhi(u.x) * w;                    \
        acc[2] += bflo(u.y) * w; acc[3] += bfhi(u.y) * w;                    \
        acc[4] += bflo(u.z) * w; acc[5] += bfhi(u.z) * w;                    \
        acc[6] += bflo(u.w) * w; acc[7] += bfhi(u.w) * w;                    \
    }
    for (int j0 = lo; j0 < hi; j0 += 32) {
        GATHER_ADD(j0 + slot)
        GATHER_ADD(j0 + 8 + slot)
        GATHER_ADD(j0 + 16 + slot)
        GATHER_ADD(j0 + 24 + slot)
    }
#undef GATHER_ADD

#pragma unroll
    for (int m = 8; m <= 32; m <<= 1) {
#pragma unroll
        for (int q = 0; q < 8; ++q) acc[q] += __shfl_xor(acc[q], m);
    }

    if (slot == 0) {
        size_t o = (size_t)n * HDIM + fo * 8;
        uint4 dv = *(const uint4*)(dbuf + o);
        float dd[8] = {bflo(dv.x), bfhi(dv.x), bflo(dv.y), bfhi(dv.y),
                       bflo(dv.z), bfhi(dv.z), bflo(dv.w), bfhi(dv.w)};
        unsigned r[4];
#pragma unroll
        for (int q = 0; q < 4; ++q) {
            unsigned lo16 = f2bf(fmaxf(acc[2 * q] + dd[2 * q], 0.f));
            unsigned hi16 = f2bf(fmaxf(acc[2 * q + 1] + dd[2 * q + 1], 0.f));
            r[q] = lo16 | (hi16 << 16);
        }
        *(uint4*)(h + o) = make_uint4(r[0], r[1], r[2], r[3]);
    }
}

// ---------------- fused mean pool + MLP head: one block per graph, 256 thr ----------------
__global__ __launch_bounds__(256) void k_poolhead(const unsigned short* __restrict__ h,
                                                  const int* __restrict__ goff,
                                                  const float* __restrict__ W1,
                                                  const float* __restrict__ b1,
                                                  const float* __restrict__ W2,
                                                  const float* __restrict__ b2,
                                                  float* __restrict__ out) {
    int g = blockIdx.x;
    __shared__ float part[256];
    __shared__ float sx[HDIM];
    __shared__ float sy[2 * HDIM];
    int t = threadIdx.x;
    int lo = goff[g], hi = goff[g + 1];
    int f = t & 63, quarter = t >> 6;
    float acc = 0.f;
    for (int n = lo + quarter; n < hi; n += 4) acc += bf1(h[(size_t)n * HDIM + f]);
    part[t] = acc;
    __syncthreads();
    if (t < HDIM)
        sx[t] = (part[t] + part[t + 64] + part[t + 128] + part[t + 192]) /
                fmaxf((float)(hi - lo), 1.f);
    __syncthreads();
    if (t < 2 * HDIM) {
        float a1 = b1[t];
        for (int k = 0; k < HDIM; ++k) a1 += sx[k] * W1[k * 2 * HDIM + t];
        sy[t] = fmaxf(a1, 0.f);
    }
    __syncthreads();
    if (t < C_CLS) {
        float o = b2[t];
        for (int k = 0; k < 2 * HDIM; ++k) o += sy[k] * W2[k * C_CLS + t];
        out[g * C_CLS + t] = o;
    }
}

extern "C" void kernel_launch(void* const* d_in, const int* in_sizes, int n_in,
                              void* d_out, int out_size, void* d_ws, size_t ws_size,
                              hipStream_t stream) {
    const float* x      = (const float*)d_in[0];
    const int*   ei     = (const int*)d_in[1];
    const float* eattr  = (const float*)d_in[2];
    const int*   batch  = (const int*)d_in[3];
    const float* w_emb  = (const float*)d_in[4];
    const float* b_emb  = (const float*)d_in[5];
    const float* lin1_w = (const float*)d_in[6];
    const float* lin1_b = (const float*)d_in[7];
    const float* lin2_w = (const float*)d_in[8];
    const float* lin3_w = (const float*)d_in[9];
    const float* lin3_b = (const float*)d_in[10];
    const float* mlp_w1 = (const float*)d_in[11];
    const float* mlp_b1 = (const float*)d_in[12];
    const float* mlp_w2 = (const float*)d_in[13];
    const float* mlp_b2 = (const float*)d_in[14];
    float* out = (float*)d_out;

    const int* src = ei;
    const int* dst = ei + N_EDGES;

    const size_t NH = (size_t)N_NODES * HDIM;
    unsigned short* abf0 = (unsigned short*)d_ws;    // NH bf16
    unsigned short* dbf0 = abf0 + NH;                // NH bf16
    unsigned short* abf1 = dbf0 + NH;                // NH bf16
    unsigned short* dbf1 = abf1 + NH;                // NH bf16
    unsigned short* h2   = dbf1 + NH;                // NH bf16
    float* wsum = (float*)(h2 + NH);                 // N
    int2* edge2 = (int2*)(wsum + N_NODES);           // E
    int2* bbuf  = edge2 + N_EDGES;                   // E
    int* off    = (int*)(bbuf + N_EDGES);            // N+1
    int* bcnt   = off + N_NODES + 1;                 // NB (zeroed)
    int* bcur   = bcnt + NB;                         // NB
    int* boff   = bcur + NB;                         // NB+1
    int* goff   = boff + NB + 1;                     // G+1
    float* wp   = (float*)(goff + G_GRAPHS + 1);     // 3*4*64
    float* bp   = wp + 3 * 256;                      // 3*64

    hipMemsetAsync(bcnt, 0, NB * sizeof(int), stream);

    k_prew<<<1, 256, 0, stream>>>(w_emb, b_emb,
                                  lin1_w, lin1_b, lin2_w, lin3_w, lin3_b, wp, bp);
    k_hist_bounds<<<HIST_BLOCKS + BNDS_BLOCKS, 256, 0, stream>>>(dst, bcnt, batch, goff);
    k_boff<<<1, 512, 0, stream>>>(bcnt, boff, bcur);
    k_bucket<<<CBLK, 1024, 0, stream>>>(src, dst, eattr, bcur, bbuf);
    k_csr<<<NB, 256, 0, stream>>>(bbuf, boff, off, wsum, edge2);

    int gemm_blocks = (N_NODES + 63) / 64;           // 1563
    int aggemm_blocks = N_NODES / 16;                // 6250 (exact)
    int agg_blocks = (N_NODES + 3) / 4;              // 25000

    k_gemm1st<<<gemm_blocks, 256, 0, stream>>>(x, wp, bp, wsum, abf0, dbf0);
    k_aggemm<<<aggemm_blocks, 256, 0, stream>>>(edge2, off, abf0, dbf0,
                                                lin1_w + HDIM * HDIM, lin1_b + HDIM,
                                                lin2_w + HDIM * HDIM,
                                                lin3_w + HDIM * HDIM, lin3_b + HDIM,
                                                wsum, abf1, dbf1);
    k_agg<<<agg_blocks, 256, 0, stream>>>(edge2, off, abf1, dbf1, h2);
    k_poolhead<<<G_GRAPHS, 256, 0, stream>>>(h2, goff, mlp_w1, mlp_b1, mlp_w2, mlp_b2, out);
}